// Round 1
// baseline (107.109 us; speedup 1.0000x reference)
//
#include <hip/hip_runtime.h>
#include <stdint.h>

#define B_    32
#define CH    64
#define T_    16384
#define NC    129     // noise coeffs
#define NFRM  128     // frames
#define WIN   256
#define QPAD  136     // padded coeff rows in spec_ws (17*8)
#define MROWS 144     // padded W rows (9 MFMA tiles)

typedef __attribute__((ext_vector_type(4))) float f32x4;
typedef __attribute__((ext_vector_type(8))) short bf16x8;

__device__ __forceinline__ unsigned short f2bs(float f) {
  union { float f; unsigned u; } v; v.f = f;
  unsigned r = (v.u + 0x7FFFu + ((v.u >> 16) & 1u)) >> 16;
  return (unsigned short)r;
}
__device__ __forceinline__ float b2f(unsigned short s) {
  union { float f; unsigned u; } v; v.u = ((unsigned)s) << 16; return v.f;
}

// ---------------------------------------------------------------------------
// k0: DFT synthesis tables, bf16.
// T1[q][m], q=0..128: cos(2*pi*q*m/256); q=129..255 (k=q-128): sin(2*pi*k*m/256)
// T2[n][q]: c_q * cos/sin(2*pi*k*n/256), c=1 for q in {0,128}, else 2.
//           (global 1/256 folded into final output scale)
// ---------------------------------------------------------------------------
__global__ __launch_bounds__(256) void k0_tables(unsigned short* __restrict__ T1,
                                                 unsigned short* __restrict__ T2) {
  int g = blockIdx.x * 256 + threadIdx.x;   // 16384 threads
  int base = g * 8;                          // element index over 2*65536
  int tab = base >> 16;
  int off = base & 65535;
  int row = off >> 8, col0 = off & 255;
  const float w0 = 6.283185307179586f / 256.f;
  bf16x8 pk;
#pragma unroll
  for (int e = 0; e < 8; ++e) {
    int cq = col0 + e;
    float v;
    if (tab == 0) {  // T1[q=row][m=cq]
      int q = row, m = cq;
      int idx = (q <= 128) ? ((q * m) & 255) : (((q - 128) * m + 192) & 255);
      v = cosf((float)idx * w0);
    } else {         // T2[n=row][q=cq]
      int n = row, q = cq;
      float c = (q == 0 || q == 128) ? 1.f : 2.f;
      int idx = (q <= 128) ? ((q * n) & 255) : (((q - 128) * n + 192) & 255);
      v = c * cosf((float)idx * w0);
    }
    pk[e] = (short)f2bs(v);
  }
  *(bf16x8*)((tab ? T2 : T1) + off) = pk;
}

// ---------------------------------------------------------------------------
// k1: per (frame j, batch b): channel mean -> out ; conv129 -> clip -> frame
//     mean -> spec_ws (bf16). HBM-bound (reads all of x once).
// ---------------------------------------------------------------------------
__global__ __launch_bounds__(256) void k1_spec_mean(
    const float* __restrict__ x, const float* __restrict__ nw,
    const float* __restrict__ nb, float* __restrict__ out,
    unsigned short* __restrict__ spec_ws) {
  __shared__ __align__(16) float xf[CH * 128];              // [c][t] 32 KB
  __shared__ __align__(16) unsigned short xbT[128 * 64];    // [t][c] swizzled
  __shared__ __align__(16) unsigned short wb[MROWS * 64];   // [q][c] swizzled
  __shared__ float bias_l[MROWS];
  __shared__ float spec_acc[MROWS];

  const int j = blockIdx.x;
  const int b = blockIdx.y;
  const int tid = threadIdx.x;
  const int lane = tid & 63;
  const int w = tid >> 6;
  const int l15 = lane & 15, l4 = lane >> 4;

  if (tid < MROWS) {
    spec_acc[tid] = 0.f;
    bias_l[tid] = (tid < NC) ? nb[tid] : 0.f;
  }

  // stage W -> bf16 swizzled (144 rows x 8 octets)
  for (int task = tid; task < MROWS * 8; task += 256) {
    int q = task >> 3, oct = task & 7;
    bf16x8 pk;
    if (q < NC) {
      const float* src = nw + q * 64 + oct * 8;
#pragma unroll
      for (int e = 0; e < 8; ++e) pk[e] = (short)f2bs(src[e]);
    } else {
#pragma unroll
      for (int e = 0; e < 8; ++e) pk[e] = 0;
    }
    unsigned a = q * 128 + oct * 16;
    a ^= ((a >> 7) & 7) << 4;
    *(bf16x8*)((char*)wb + a) = pk;
  }

  // stage x tile (64 ch x 128 t) fp32
  {
    const float* xg = x + (size_t)b * CH * T_ + j * 128;
    for (int it = 0; it < 8; ++it) {
      int r = it * 8 + (tid >> 5);
      int c16 = tid & 31;
      f32x4 v = *(const f32x4*)(xg + (size_t)r * T_ + c16 * 4);
      *(f32x4*)(xf + r * 128 + c16 * 4) = v;
    }
  }
  __syncthreads();

  // channel mean -> out (fp32, exact path)
  if (tid < 128) {
    float s = 0.f;
#pragma unroll 8
    for (int c = 0; c < 64; ++c) s += xf[c * 128 + tid];
    out[(size_t)b * T_ + j * 128 + tid] = s * (1.f / 64.f);
  }

  // convert x -> bf16 transposed swizzled [t][c]
  for (int task = tid; task < 1024; task += 256) {
    int t = task & 127, oct = task >> 7;
    bf16x8 pk;
#pragma unroll
    for (int e = 0; e < 8; ++e) pk[e] = (short)f2bs(xf[(oct * 8 + e) * 128 + t]);
    unsigned a = t * 128 + oct * 16;
    a ^= ((a >> 7) & 7) << 4;
    *(bf16x8*)((char*)xbT + a) = pk;
  }
  __syncthreads();

  // MFMA conv: wave w handles t-tiles {2w, 2w+1}
  const f32x4 fz = {0.f, 0.f, 0.f, 0.f};
  f32x4 acc[9][2];
#pragma unroll
  for (int m = 0; m < 9; ++m) { acc[m][0] = fz; acc[m][1] = fz; }
#pragma unroll
  for (int kt = 0; kt < 2; ++kt) {
    bf16x8 bfr[2];
#pragma unroll
    for (int p = 0; p < 2; ++p) {
      int t = (2 * w + p) * 16 + l15;
      unsigned a = t * 128 + kt * 64 + l4 * 16;
      a ^= ((a >> 7) & 7) << 4;
      bfr[p] = *(const bf16x8*)((const char*)xbT + a);
    }
#pragma unroll
    for (int m = 0; m < 9; ++m) {
      int q = m * 16 + l15;
      unsigned a = q * 128 + kt * 64 + l4 * 16;
      a ^= ((a >> 7) & 7) << 4;
      bf16x8 afr = *(const bf16x8*)((const char*)wb + a);
      acc[m][0] = __builtin_amdgcn_mfma_f32_16x16x32_bf16(afr, bfr[0], acc[m][0], 0, 0, 0);
      acc[m][1] = __builtin_amdgcn_mfma_f32_16x16x32_bf16(afr, bfr[1], acc[m][1], 0, 0, 0);
    }
  }
  // bias + clip + frame-average (sum over 128 t)
#pragma unroll
  for (int m = 0; m < 9; ++m) {
#pragma unroll
    for (int r = 0; r < 4; ++r) {
      int q = m * 16 + l4 * 4 + r;
      float bq = bias_l[q];
      float v0 = fminf(fmaxf(acc[m][0][r] + bq, 0.f), 1.f);
      float v1 = fminf(fmaxf(acc[m][1][r] + bq, 0.f), 1.f);
      float v = v0 + v1;
      v += __shfl_xor(v, 1);
      v += __shfl_xor(v, 2);
      v += __shfl_xor(v, 4);
      v += __shfl_xor(v, 8);
      if (l15 == 0) atomicAdd(&spec_acc[q], v);
    }
  }
  __syncthreads();
  if (tid < QPAD) {
    float v = (tid < NC) ? spec_acc[tid] * (1.f / 128.f) : 0.f;
    spec_ws[((size_t)b * NFRM + j) * QPAD + tid] = f2bs(v);
  }
}

// ---------------------------------------------------------------------------
// k2: noise bank. Block = (chunk of 32 frames, batch). Slots s=0..47 map to
// frames j = c*32-1+s (slot 0 = tail provider; spec=0 for j<0 handles c=0).
// GEMM1: CS = T1 * frames ; G = spec .* CS ; GEMM2: audio = T2 * G ; OLA.
// ---------------------------------------------------------------------------
__global__ __launch_bounds__(512) void k2_noise(
    const float* __restrict__ white, const unsigned short* __restrict__ spec_ws,
    const unsigned short* __restrict__ T1, const unsigned short* __restrict__ T2,
    const float* __restrict__ nf_p, float* __restrict__ out) {
  __shared__ __align__(16) unsigned short wn[6400];          // frames src, swz
  __shared__ __align__(16) unsigned short spec_l[48 * QPAD]; // [s][k]
  __shared__ __align__(16) unsigned short G[48 * 256];       // [s][q], swz
  __shared__ __align__(16) float audio[256 * 49];            // [n][s], pad 49

  const int c = blockIdx.x, b = blockIdx.y;
  const int jb = c * 32 - 1;
  const int tid = threadIdx.x;
  const int lane = tid & 63, w = tid >> 6;
  const int l15 = lane & 15, l4 = lane >> 4;

  // stage white -> bf16 swizzled frames source (relative idx r = s*128+m)
  for (int rc = tid; rc < 800; rc += 512) {
    int g0 = jb * 128 + rc * 8;
    bf16x8 pk;
    if ((unsigned)g0 < (unsigned)T_) {  // 8-aligned boundaries -> whole chunk
      f32x4 lo = *(const f32x4*)(white + (size_t)b * T_ + g0);
      f32x4 hi = *(const f32x4*)(white + (size_t)b * T_ + g0 + 4);
#pragma unroll
      for (int e = 0; e < 4; ++e) { pk[e] = (short)f2bs(lo[e]); pk[e + 4] = (short)f2bs(hi[e]); }
    } else {
#pragma unroll
      for (int e = 0; e < 8; ++e) pk[e] = 0;
    }
    unsigned a = rc * 16;
    a ^= ((a >> 8) & 7) << 4;
    *(bf16x8*)((char*)wn + a) = pk;
  }
  // stage spec (48 slots x 136 coeffs, bf16), zeros for out-of-range frames
  for (int ec = tid; ec < 48 * 17; ec += 512) {
    int s = ec / 17, cr = ec % 17;
    int j = jb + s;
    uint4 v = make_uint4(0u, 0u, 0u, 0u);
    if ((unsigned)j < 128u)
      v = *(const uint4*)(spec_ws + ((size_t)b * NFRM + j) * QPAD + cr * 8);
    *(uint4*)(spec_l + s * QPAD + cr * 8) = v;
  }
  __syncthreads();

  const f32x4 fz = {0.f, 0.f, 0.f, 0.f};
  // GEMM1: CS[q, s] = sum_m T1[q,m] * frames[m,s]
  f32x4 acc[2][3];
#pragma unroll
  for (int mi = 0; mi < 2; ++mi)
#pragma unroll
    for (int nt = 0; nt < 3; ++nt) acc[mi][nt] = fz;
#pragma unroll
  for (int kt = 0; kt < 8; ++kt) {
    bf16x8 bfr[3];
#pragma unroll
    for (int nt = 0; nt < 3; ++nt) {
      int s = nt * 16 + l15;
      unsigned a = s * 256 + kt * 64 + l4 * 16;
      a ^= ((a >> 8) & 7) << 4;
      bfr[nt] = *(const bf16x8*)((const char*)wn + a);
    }
#pragma unroll
    for (int mi = 0; mi < 2; ++mi) {
      int q = (2 * w + mi) * 16 + l15;
      bf16x8 afr = *(const bf16x8*)(T1 + q * 256 + kt * 32 + l4 * 8);
#pragma unroll
      for (int nt = 0; nt < 3; ++nt)
        acc[mi][nt] = __builtin_amdgcn_mfma_f32_16x16x32_bf16(afr, bfr[nt], acc[mi][nt], 0, 0, 0);
    }
  }
  // scale by spec -> G (bf16, swizzled), packed pair writes
#pragma unroll
  for (int mi = 0; mi < 2; ++mi) {
    int qbase = (2 * w + mi) * 16 + l4 * 4;
#pragma unroll
    for (int nt = 0; nt < 3; ++nt) {
      int s = nt * 16 + l15;
#pragma unroll
      for (int rp = 0; rp < 2; ++rp) {
        int q0 = qbase + rp * 2;
        int k0 = (q0 <= 128) ? q0 : q0 - 128;
        int k1 = (q0 + 1 <= 128) ? q0 + 1 : q0 - 127;
        float s0 = b2f(spec_l[s * QPAD + k0]);
        float s1 = b2f(spec_l[s * QPAD + k1]);
        unsigned lo = f2bs(acc[mi][nt][rp * 2] * s0);
        unsigned hi = f2bs(acc[mi][nt][rp * 2 + 1] * s1);
        unsigned a = s * 512 + q0 * 2;
        a ^= ((a >> 9) & 7) << 4;
        *(unsigned*)((char*)G + a) = lo | (hi << 16);
      }
    }
  }
  __syncthreads();

  // GEMM2: audio[n, s] = sum_q T2[n,q] * G[q,s]
  f32x4 acc2[2][3];
#pragma unroll
  for (int mi = 0; mi < 2; ++mi)
#pragma unroll
    for (int nt = 0; nt < 3; ++nt) acc2[mi][nt] = fz;
#pragma unroll
  for (int kt = 0; kt < 8; ++kt) {
    bf16x8 bfr[3];
#pragma unroll
    for (int nt = 0; nt < 3; ++nt) {
      int s = nt * 16 + l15;
      unsigned a = s * 512 + kt * 64 + l4 * 16;
      a ^= ((a >> 9) & 7) << 4;
      bfr[nt] = *(const bf16x8*)((const char*)G + a);
    }
#pragma unroll
    for (int mi = 0; mi < 2; ++mi) {
      int n = (2 * w + mi) * 16 + l15;
      bf16x8 afr = *(const bf16x8*)(T2 + n * 256 + kt * 32 + l4 * 8);
#pragma unroll
      for (int nt = 0; nt < 3; ++nt)
        acc2[mi][nt] = __builtin_amdgcn_mfma_f32_16x16x32_bf16(afr, bfr[nt], acc2[mi][nt], 0, 0, 0);
    }
  }
  // write audio to LDS [n][s] (pad 49 -> conflict-free)
#pragma unroll
  for (int mi = 0; mi < 2; ++mi)
#pragma unroll
    for (int nt = 0; nt < 3; ++nt)
#pragma unroll
      for (int r = 0; r < 4; ++r) {
        int n = (2 * w + mi) * 16 + l4 * 4 + r;
        int s = nt * 16 + l15;
        audio[n * 49 + s] = acc2[mi][nt][r];
      }
  __syncthreads();

  // OLA + scaled add into out (out already holds the channel mean)
  const float cf = nf_p[0] * (1.f / 256.f);
  for (int i = tid; i < 1024; i += 512) {
    int t0 = i * 4;             // [0, 4096) within this chunk
    int n = t0 & 127, jl = t0 >> 7;
    int s1 = jl + 1;            // slot of frame c*32+jl
    size_t o = (size_t)b * T_ + c * 4096 + t0;
    f32x4 ov = *(f32x4*)(out + o);
#pragma unroll
    for (int e = 0; e < 4; ++e) {
      float a1 = audio[(n + e) * 49 + s1];
      float a2 = audio[(n + e + 128) * 49 + (s1 - 1)];
      ov[e] += cf * (a1 + a2);
    }
    *(f32x4*)(out + o) = ov;
  }
}

// ---------------------------------------------------------------------------
extern "C" void kernel_launch(void* const* d_in, const int* in_sizes, int n_in,
                              void* d_out, int out_size, void* d_ws, size_t ws_size,
                              hipStream_t stream) {
  (void)in_sizes; (void)n_in; (void)out_size; (void)ws_size;
  const float* x            = (const float*)d_in[0];
  const float* noise_w      = (const float*)d_in[5];
  const float* noise_b      = (const float*)d_in[6];
  const float* noise_factor = (const float*)d_in[7];
  const float* white        = (const float*)d_in[8];
  float* out = (float*)d_out;

  unsigned short* T1   = (unsigned short*)d_ws;           // 65536 bf16
  unsigned short* T2   = T1 + 65536;                      // 65536 bf16
  unsigned short* spec = T2 + 65536;                      // 32*128*136 bf16

  k0_tables<<<64, 256, 0, stream>>>(T1, T2);
  k1_spec_mean<<<dim3(NFRM, B_), 256, 0, stream>>>(x, noise_w, noise_b, out, spec);
  k2_noise<<<dim3(4, B_), 512, 0, stream>>>(white, spec, T1, T2, noise_factor, out);
}

// Round 2
// 75.786 us; speedup vs baseline: 1.4133x; 1.4133x over previous
//
#include <hip/hip_runtime.h>
#include <stdint.h>

#define B_    32
#define CH    64
#define T_    16384
#define NC    129     // noise coeffs
#define NFRM  128     // frames
#define WIN   256
#define QPAD  136     // padded coeff rows in spec_ws (17*8)
#define MROWS 144     // padded W rows (9 MFMA tiles)

typedef __attribute__((ext_vector_type(4))) float f32x4;
typedef __attribute__((ext_vector_type(8))) short bf16x8;

__device__ __forceinline__ unsigned short f2bs(float f) {
  union { float f; unsigned u; } v; v.f = f;
  unsigned r = (v.u + 0x7FFFu + ((v.u >> 16) & 1u)) >> 16;
  return (unsigned short)r;
}
__device__ __forceinline__ float b2f(unsigned short s) {
  union { float f; unsigned u; } v; v.u = ((unsigned)s) << 16; return v.f;
}

#define GLOAD_LDS16(g, l) \
  __builtin_amdgcn_global_load_lds((const __attribute__((address_space(1))) void*)(g), \
                                   (__attribute__((address_space(3))) void*)(l), 16, 0, 0)

// ---------------------------------------------------------------------------
// k0: DFT synthesis tables, bf16 (unchanged).
// ---------------------------------------------------------------------------
__global__ __launch_bounds__(256) void k0_tables(unsigned short* __restrict__ T1,
                                                 unsigned short* __restrict__ T2) {
  int g = blockIdx.x * 256 + threadIdx.x;
  int base = g * 8;
  int tab = base >> 16;
  int off = base & 65535;
  int row = off >> 8, col0 = off & 255;
  const float w0 = 6.283185307179586f / 256.f;
  bf16x8 pk;
#pragma unroll
  for (int e = 0; e < 8; ++e) {
    int cq = col0 + e;
    float v;
    if (tab == 0) {
      int q = row, m = cq;
      int idx = (q <= 128) ? ((q * m) & 255) : (((q - 128) * m + 192) & 255);
      v = cosf((float)idx * w0);
    } else {
      int n = row, q = cq;
      float c = (q == 0 || q == 128) ? 1.f : 2.f;
      int idx = (q <= 128) ? ((q * n) & 255) : (((q - 128) * n + 192) & 255);
      v = c * cosf((float)idx * w0);
    }
    pk[e] = (short)f2bs(v);
  }
  *(bf16x8*)((tab ? T2 : T1) + off) = pk;
}

// ---------------------------------------------------------------------------
// k0b: pack W -> bf16 swizzled octets (same layout k1's MFMA reads), bias fp32.
// One-time; k1 then stages it with async global_load_lds (no per-block VALU).
// ---------------------------------------------------------------------------
__global__ __launch_bounds__(256) void k0b_pack(const float* __restrict__ nw,
                                                const float* __restrict__ nb,
                                                unsigned short* __restrict__ wb_ws,
                                                float* __restrict__ bias_ws) {
  int tid = blockIdx.x * 256 + threadIdx.x;
  if (tid < MROWS * 8) {
    int q = tid >> 3, oct = tid & 7;
    bf16x8 pk;
    if (q < NC) {
      const float* src = nw + q * 64 + oct * 8;
#pragma unroll
      for (int e = 0; e < 8; ++e) pk[e] = (short)f2bs(src[e]);
    } else {
#pragma unroll
      for (int e = 0; e < 8; ++e) pk[e] = 0;
    }
    unsigned a = q * 128 + oct * 16;
    a ^= ((a >> 7) & 7) << 4;
    *(bf16x8*)((char*)wb_ws + a) = pk;
  }
  if (tid < MROWS) bias_ws[tid] = (tid < NC) ? nb[tid] : 0.f;
}

// ---------------------------------------------------------------------------
// k1 v2: register-direct. Thread (g=tid>>5, c16=tid&31) loads rows g*8+it
// (it=0..7) at t-quad c16*4 -> holds an 8c x 4t register block.
//   mean: sum 8 rows + shfl_xor(32) -> LDS[4][32] partials -> 128 threads final
//   xbT:  4 bf16x8 octets (t=c16*4+e, oct=g), swizzle ((t^(t>>3))&7)<<4
//   W:    async global_load_lds from pre-packed ws
// ---------------------------------------------------------------------------
__global__ __launch_bounds__(256, 4) void k1_spec_mean(
    const float* __restrict__ x, const unsigned short* __restrict__ wb_ws,
    const float* __restrict__ bias_ws, float* __restrict__ out,
    unsigned short* __restrict__ spec_ws) {
  __shared__ __align__(16) unsigned short xbT[128 * 64];    // 16 KB swizzled
  __shared__ __align__(16) unsigned short wb[MROWS * 64];   // 18 KB swizzled
  __shared__ __align__(16) f32x4 mean_acc[4][32];           // 2 KB
  __shared__ float bias_l[MROWS];
  __shared__ float spec_acc[MROWS];

  const int j = blockIdx.x;
  const int b = blockIdx.y;
  const int tid = threadIdx.x;
  const int lane = tid & 63;
  const int w = tid >> 6;
  const int l15 = lane & 15, l4 = lane >> 4;
  const int g = tid >> 5, c16 = tid & 31;

  if (tid < MROWS) {
    spec_acc[tid] = 0.f;
    bias_l[tid] = bias_ws[tid];
  }

  // async W stage: 1152 16B-octets, linear copy (layout pre-swizzled in ws)
#pragma unroll
  for (int k = 0; k < 5; ++k) {
    int task = k * 256 + tid;
    if (task < MROWS * 8) {
      const char* gp = (const char*)wb_ws + (size_t)task * 16;
      char* lp = (char*)wb + (size_t)(k * 256 + w * 64) * 16;  // wave-uniform
      GLOAD_LDS16(gp, lp);
    }
  }

  // x loads: 8 per thread, independent
  const float* xg = x + (size_t)b * CH * T_ + j * 128 + c16 * 4;
  f32x4 v[8];
#pragma unroll
  for (int it = 0; it < 8; ++it)
    v[it] = *(const f32x4*)(xg + (size_t)(g * 8 + it) * T_);

  // channel-mean partial: 8 consecutive c, then xor-32 -> 16-c partial
  f32x4 ms = v[0] + v[1] + v[2] + v[3] + v[4] + v[5] + v[6] + v[7];
  f32x4 os;
#pragma unroll
  for (int e = 0; e < 4; ++e) os[e] = __shfl_xor(ms[e], 32);
  ms += os;
  if (lane < 32) mean_acc[w][c16] = ms;

  // bf16 transpose in-register -> swizzled xbT
#pragma unroll
  for (int e = 0; e < 4; ++e) {
    bf16x8 pk;
#pragma unroll
    for (int it = 0; it < 8; ++it) pk[it] = (short)f2bs(v[it][e]);
    int t = c16 * 4 + e;
    unsigned a = (unsigned)(t * 128 + g * 16);
    a ^= (((t ^ (t >> 3)) & 7) << 4);
    *(bf16x8*)((char*)xbT + a) = pk;
  }
  __syncthreads();   // drains global_load_lds (vmcnt) + LDS writes

  // channel mean -> out (fp32 path), overlaps MFMA on other waves
  if (tid < 128) {
    int q4 = tid >> 2, e4 = tid & 3;
    float s = mean_acc[0][q4][e4] + mean_acc[1][q4][e4] +
              mean_acc[2][q4][e4] + mean_acc[3][q4][e4];
    out[(size_t)b * T_ + j * 128 + tid] = s * (1.f / 64.f);
  }

  // MFMA conv: wave w -> t-tiles {2w, 2w+1}
  const f32x4 fz = {0.f, 0.f, 0.f, 0.f};
  f32x4 acc[9][2];
#pragma unroll
  for (int m = 0; m < 9; ++m) { acc[m][0] = fz; acc[m][1] = fz; }
#pragma unroll
  for (int kt = 0; kt < 2; ++kt) {
    bf16x8 bfr[2];
#pragma unroll
    for (int p = 0; p < 2; ++p) {
      int t = (2 * w + p) * 16 + l15;
      unsigned a = (unsigned)(t * 128 + kt * 64 + l4 * 16);
      a ^= (((t ^ (t >> 3)) & 7) << 4);
      bfr[p] = *(const bf16x8*)((const char*)xbT + a);
    }
#pragma unroll
    for (int m = 0; m < 9; ++m) {
      int q = m * 16 + l15;
      unsigned a = (unsigned)(q * 128 + kt * 64 + l4 * 16);
      a ^= ((a >> 7) & 7) << 4;
      bf16x8 afr = *(const bf16x8*)((const char*)wb + a);
      acc[m][0] = __builtin_amdgcn_mfma_f32_16x16x32_bf16(afr, bfr[0], acc[m][0], 0, 0, 0);
      acc[m][1] = __builtin_amdgcn_mfma_f32_16x16x32_bf16(afr, bfr[1], acc[m][1], 0, 0, 0);
    }
  }
  // bias + clip + frame-sum (over 128 t)
#pragma unroll
  for (int m = 0; m < 9; ++m) {
#pragma unroll
    for (int r = 0; r < 4; ++r) {
      int q = m * 16 + l4 * 4 + r;
      float bq = bias_l[q];
      float v0 = fminf(fmaxf(acc[m][0][r] + bq, 0.f), 1.f);
      float v1 = fminf(fmaxf(acc[m][1][r] + bq, 0.f), 1.f);
      float s = v0 + v1;
      s += __shfl_xor(s, 1);
      s += __shfl_xor(s, 2);
      s += __shfl_xor(s, 4);
      s += __shfl_xor(s, 8);
      if (l15 == 0) atomicAdd(&spec_acc[q], s);
    }
  }
  __syncthreads();
  if (tid < QPAD) {
    float sv = (tid < NC) ? spec_acc[tid] * (1.f / 128.f) : 0.f;
    spec_ws[((size_t)b * NFRM + j) * QPAD + tid] = f2bs(sv);
  }
}

// ---------------------------------------------------------------------------
// k2: noise bank (unchanged this round).
// ---------------------------------------------------------------------------
__global__ __launch_bounds__(512) void k2_noise(
    const float* __restrict__ white, const unsigned short* __restrict__ spec_ws,
    const unsigned short* __restrict__ T1, const unsigned short* __restrict__ T2,
    const float* __restrict__ nf_p, float* __restrict__ out) {
  __shared__ __align__(16) unsigned short wn[6400];
  __shared__ __align__(16) unsigned short spec_l[48 * QPAD];
  __shared__ __align__(16) unsigned short G[48 * 256];
  __shared__ __align__(16) float audio[256 * 49];

  const int c = blockIdx.x, b = blockIdx.y;
  const int jb = c * 32 - 1;
  const int tid = threadIdx.x;
  const int lane = tid & 63, w = tid >> 6;
  const int l15 = lane & 15, l4 = lane >> 4;

  for (int rc = tid; rc < 800; rc += 512) {
    int g0 = jb * 128 + rc * 8;
    bf16x8 pk;
    if ((unsigned)g0 < (unsigned)T_) {
      f32x4 lo = *(const f32x4*)(white + (size_t)b * T_ + g0);
      f32x4 hi = *(const f32x4*)(white + (size_t)b * T_ + g0 + 4);
#pragma unroll
      for (int e = 0; e < 4; ++e) { pk[e] = (short)f2bs(lo[e]); pk[e + 4] = (short)f2bs(hi[e]); }
    } else {
#pragma unroll
      for (int e = 0; e < 8; ++e) pk[e] = 0;
    }
    unsigned a = rc * 16;
    a ^= ((a >> 8) & 7) << 4;
    *(bf16x8*)((char*)wn + a) = pk;
  }
  for (int ec = tid; ec < 48 * 17; ec += 512) {
    int s = ec / 17, cr = ec % 17;
    int jj = jb + s;
    uint4 vv = make_uint4(0u, 0u, 0u, 0u);
    if ((unsigned)jj < 128u)
      vv = *(const uint4*)(spec_ws + ((size_t)b * NFRM + jj) * QPAD + cr * 8);
    *(uint4*)(spec_l + s * QPAD + cr * 8) = vv;
  }
  __syncthreads();

  const f32x4 fz = {0.f, 0.f, 0.f, 0.f};
  f32x4 acc[2][3];
#pragma unroll
  for (int mi = 0; mi < 2; ++mi)
#pragma unroll
    for (int nt = 0; nt < 3; ++nt) acc[mi][nt] = fz;
#pragma unroll
  for (int kt = 0; kt < 8; ++kt) {
    bf16x8 bfr[3];
#pragma unroll
    for (int nt = 0; nt < 3; ++nt) {
      int s = nt * 16 + l15;
      unsigned a = s * 256 + kt * 64 + l4 * 16;
      a ^= ((a >> 8) & 7) << 4;
      bfr[nt] = *(const bf16x8*)((const char*)wn + a);
    }
#pragma unroll
    for (int mi = 0; mi < 2; ++mi) {
      int q = (2 * w + mi) * 16 + l15;
      bf16x8 afr = *(const bf16x8*)(T1 + q * 256 + kt * 32 + l4 * 8);
#pragma unroll
      for (int nt = 0; nt < 3; ++nt)
        acc[mi][nt] = __builtin_amdgcn_mfma_f32_16x16x32_bf16(afr, bfr[nt], acc[mi][nt], 0, 0, 0);
    }
  }
#pragma unroll
  for (int mi = 0; mi < 2; ++mi) {
    int qbase = (2 * w + mi) * 16 + l4 * 4;
#pragma unroll
    for (int nt = 0; nt < 3; ++nt) {
      int s = nt * 16 + l15;
#pragma unroll
      for (int rp = 0; rp < 2; ++rp) {
        int q0 = qbase + rp * 2;
        int kk0 = (q0 <= 128) ? q0 : q0 - 128;
        int kk1 = (q0 + 1 <= 128) ? q0 + 1 : q0 - 127;
        float s0 = b2f(spec_l[s * QPAD + kk0]);
        float s1 = b2f(spec_l[s * QPAD + kk1]);
        unsigned lo = f2bs(acc[mi][nt][rp * 2] * s0);
        unsigned hi = f2bs(acc[mi][nt][rp * 2 + 1] * s1);
        unsigned a = s * 512 + q0 * 2;
        a ^= ((a >> 9) & 7) << 4;
        *(unsigned*)((char*)G + a) = lo | (hi << 16);
      }
    }
  }
  __syncthreads();

  f32x4 acc2[2][3];
#pragma unroll
  for (int mi = 0; mi < 2; ++mi)
#pragma unroll
    for (int nt = 0; nt < 3; ++nt) acc2[mi][nt] = fz;
#pragma unroll
  for (int kt = 0; kt < 8; ++kt) {
    bf16x8 bfr[3];
#pragma unroll
    for (int nt = 0; nt < 3; ++nt) {
      int s = nt * 16 + l15;
      unsigned a = s * 512 + kt * 64 + l4 * 16;
      a ^= ((a >> 9) & 7) << 4;
      bfr[nt] = *(const bf16x8*)((const char*)G + a);
    }
#pragma unroll
    for (int mi = 0; mi < 2; ++mi) {
      int n = (2 * w + mi) * 16 + l15;
      bf16x8 afr = *(const bf16x8*)(T2 + n * 256 + kt * 32 + l4 * 8);
#pragma unroll
      for (int nt = 0; nt < 3; ++nt)
        acc2[mi][nt] = __builtin_amdgcn_mfma_f32_16x16x32_bf16(afr, bfr[nt], acc2[mi][nt], 0, 0, 0);
    }
  }
#pragma unroll
  for (int mi = 0; mi < 2; ++mi)
#pragma unroll
    for (int nt = 0; nt < 3; ++nt)
#pragma unroll
      for (int r = 0; r < 4; ++r) {
        int n = (2 * w + mi) * 16 + l4 * 4 + r;
        int s = nt * 16 + l15;
        audio[n * 49 + s] = acc2[mi][nt][r];
      }
  __syncthreads();

  const float cf = nf_p[0] * (1.f / 256.f);
  for (int i = tid; i < 1024; i += 512) {
    int t0 = i * 4;
    int n = t0 & 127, jl = t0 >> 7;
    int s1 = jl + 1;
    size_t o = (size_t)b * T_ + c * 4096 + t0;
    f32x4 ov = *(f32x4*)(out + o);
#pragma unroll
    for (int e = 0; e < 4; ++e) {
      float a1 = audio[(n + e) * 49 + s1];
      float a2 = audio[(n + e + 128) * 49 + (s1 - 1)];
      ov[e] += cf * (a1 + a2);
    }
    *(f32x4*)(out + o) = ov;
  }
}

// ---------------------------------------------------------------------------
extern "C" void kernel_launch(void* const* d_in, const int* in_sizes, int n_in,
                              void* d_out, int out_size, void* d_ws, size_t ws_size,
                              hipStream_t stream) {
  (void)in_sizes; (void)n_in; (void)out_size; (void)ws_size;
  const float* x            = (const float*)d_in[0];
  const float* noise_w      = (const float*)d_in[5];
  const float* noise_b      = (const float*)d_in[6];
  const float* noise_factor = (const float*)d_in[7];
  const float* white        = (const float*)d_in[8];
  float* out = (float*)d_out;

  unsigned short* T1    = (unsigned short*)d_ws;           // 65536 bf16
  unsigned short* T2    = T1 + 65536;                      // 65536 bf16
  unsigned short* spec  = T2 + 65536;                      // 32*128*136 bf16
  unsigned short* wb_ws = spec + (size_t)B_ * NFRM * QPAD; // 1152 swz octets
  float*          bias_ws = (float*)(wb_ws + MROWS * 64);  // 144 f32

  k0_tables<<<64, 256, 0, stream>>>(T1, T2);
  k0b_pack<<<5, 256, 0, stream>>>(noise_w, noise_b, wb_ws, bias_ws);
  k1_spec_mean<<<dim3(NFRM, B_), 256, 0, stream>>>(x, wb_ws, bias_ws, out, spec);
  k2_noise<<<dim3(4, B_), 512, 0, stream>>>(white, spec, T1, T2, noise_factor, out);
}